// Round 9
// baseline (50.597 us; speedup 1.0000x reference)
//
#include <hip/hip_runtime.h>
#include <math.h>

#define D 256
#define TWOD 512
#define BB 1024
#define NN 131072
#define LOG2E 1.4426950408889634f

typedef float v4f __attribute__((ext_vector_type(4)));

__device__ __forceinline__ v4f ldg_nt(const float* p, bool valid) {
  v4f z = {0.f, 0.f, 0.f, 0.f};
  if (valid) z = __builtin_nontemporal_load((const v4f*)p);
  return z;
}

__device__ __forceinline__ float dot4(v4f a, v4f b) {
  return fmaf(a.w, b.w, fmaf(a.z, b.z, fmaf(a.y, b.y, a.x * b.x)));
}

// ---------------- prep:
// blocks 0..63    : Mt[d][k] = sum_e Wq[e][d]*Wk[e][k]        (4 d-rows/block)
// blocks 64..127  : WfT[256+h][d] = P[d][h] = sum_v Wo[d][256+v]*Wv[v][h]  (4 h/block)
// blocks 128..143 : WfT[k][d] = Wo[d][k]  (transpose of Wo_A)
// block 144       : bqt[k] = sum_e Wk[e][k]*bq[e]
// block 145       : c[d] = bo[d] + sum_v Wo[d][256+v]*bv[v]
// blocks 146..657 : offs scatter
__global__ __launch_bounds__(256) void prep_kernel(
    const float* __restrict__ Wq, const float* __restrict__ bq,
    const float* __restrict__ Wk, const float* __restrict__ Wv,
    const float* __restrict__ bv, const float* __restrict__ Wo,
    const float* __restrict__ bo, const int* __restrict__ bidx,
    float* __restrict__ Mt, float* __restrict__ WfT,
    float* __restrict__ bqt, float* __restrict__ cvec,
    int* __restrict__ offs) {
  const int blk = blockIdx.x;
  const int t = threadIdx.x;
  if (blk < 64) {
    const int d0 = blk * 4;
    float a0 = 0.f, a1 = 0.f, a2 = 0.f, a3 = 0.f;
    for (int e = 0; e < D; ++e) {
      const float wk = Wk[(size_t)e * D + t];        // coalesced
      const float* wqr = Wq + (size_t)e * D + d0;    // uniform -> sgpr
      a0 = fmaf(wqr[0], wk, a0);
      a1 = fmaf(wqr[1], wk, a1);
      a2 = fmaf(wqr[2], wk, a2);
      a3 = fmaf(wqr[3], wk, a3);
    }
    Mt[(size_t)(d0 + 0) * D + t] = a0;
    Mt[(size_t)(d0 + 1) * D + t] = a1;
    Mt[(size_t)(d0 + 2) * D + t] = a2;
    Mt[(size_t)(d0 + 3) * D + t] = a3;
  } else if (blk < 128) {
    const int h0 = (blk - 64) * 4;
    float a0 = 0.f, a1 = 0.f, a2 = 0.f, a3 = 0.f;
    for (int v = 0; v < D; ++v) {
      const float wo = Wo[(size_t)t * TWOD + D + v]; // per-lane own-row walk (L1)
      const float* wvr = Wv + (size_t)v * D + h0;    // uniform -> sgpr
      a0 = fmaf(wvr[0], wo, a0);
      a1 = fmaf(wvr[1], wo, a1);
      a2 = fmaf(wvr[2], wo, a2);
      a3 = fmaf(wvr[3], wo, a3);
    }
    WfT[(size_t)(D + h0 + 0) * D + t] = a0;
    WfT[(size_t)(D + h0 + 1) * D + t] = a1;
    WfT[(size_t)(D + h0 + 2) * D + t] = a2;
    WfT[(size_t)(D + h0 + 3) * D + t] = a3;
  } else if (blk < 144) {
    __shared__ float tile[64][65];
    const int b = blk - 128;
    const int r0 = (b >> 2) * 64, c0 = (b & 3) * 64;
    const int lane = t & 63, sr = t >> 6;
    #pragma unroll 4
    for (int rr = 0; rr < 16; ++rr) {
      const int r = rr * 4 + sr;
      tile[r][lane] = Wo[(size_t)(r0 + r) * TWOD + c0 + lane];
    }
    __syncthreads();
    #pragma unroll 4
    for (int rr = 0; rr < 16; ++rr) {
      const int r = rr * 4 + sr;
      WfT[(size_t)(c0 + r) * D + r0 + lane] = tile[lane][r];
    }
  } else if (blk == 144) {
    float a = 0.f;
    for (int e = 0; e < D; ++e)
      a = fmaf(Wk[(size_t)e * D + t], bq[e], a);
    bqt[t] = a;
  } else if (blk == 145) {
    float a = bo[t];
    for (int v = 0; v < D; ++v)
      a = fmaf(Wo[(size_t)t * TWOD + D + v], bv[v], a);
    cvec[t] = a;
  } else {
    const int i = (blk - 146) * 256 + t;
    if (i >= NN) return;
    const int b1 = bidx[i];
    const int b2 = (i + 1 < NN) ? bidx[i + 1] : BB;
    if (i == 0) {
      for (int b = 0; b <= b1; ++b) offs[b] = 0;
    }
    for (int b = b1 + 1; b <= b2; ++b) offs[b] = i + 1;
  }
}

// ---------------- fused: qt-GEMV + flash + merge + epilogue GEMV, 2 batches/block
// 512 blocks x 512 threads (8 waves) -> 3-4 blocks/CU co-resident
__global__ __launch_bounds__(512) void f_kernel(
    const float* __restrict__ H, const float* __restrict__ V,
    const float* __restrict__ Mt, const float* __restrict__ bqt,
    const int* __restrict__ offs, const float* __restrict__ WfT,
    const float* __restrict__ cvec, float* __restrict__ out) {
  __shared__ __align__(16) char smem[8192 + 2048 + 4096];
  // region A [0,8192): partq[4][2][256] -> flash ss[8][256] -> epi part[4][2][256]
  // region B [8192,10240): Vs[2][256]
  // region C [10240,14336): Us2[512][2]
  float (*partq)[2][D] = (float(*)[2][D])smem;
  float (*ss)[D] = (float(*)[D])smem;
  float (*part)[2][D] = (float(*)[2][D])smem;
  float* Vs  = (float*)(smem + 8192);
  float* Us2 = (float*)(smem + 10240);
  __shared__ float sm[8], sd[8];

  const int t = threadIdx.x;
  const int wave = t >> 6, lane = t & 63;
  const int blk = blockIdx.x;
  const int b0 = blk * 2;

  // ---- stage V
  {
    const int i = t >> 8, d = t & 255;
    Vs[i * 256 + d] = V[(size_t)(b0 + i) * D + d];
  }
  __syncthreads();

  // ---- qt prologue: qt = Mt^T V + bqt ; wave covers d in [wave*32,+32)
  {
    v4f a0 = {0.f, 0.f, 0.f, 0.f}, a1 = a0;
    const int db = wave * 32;
    #pragma unroll 4
    for (int dd = 0; dd < 32; ++dd) {
      const int d = db + dd;
      const v4f w4 = *(const v4f*)(Mt + (size_t)d * D + lane * 4);
      a0 += w4 * Vs[0 * 256 + d];
      a1 += w4 * Vs[1 * 256 + d];
    }
    if (wave >= 4) {
      *(v4f*)&partq[wave - 4][0][lane * 4] = a0;
      *(v4f*)&partq[wave - 4][1][lane * 4] = a1;
    }
    __syncthreads();
    if (wave < 4) {
      v4f p0 = *(const v4f*)&partq[wave][0][lane * 4];
      v4f p1 = *(const v4f*)&partq[wave][1][lane * 4];
      *(v4f*)&partq[wave][0][lane * 4] = a0 + p0;
      *(v4f*)&partq[wave][1][lane * 4] = a1 + p1;
    }
  }
  __syncthreads();

  // ---- flash: wave w -> batch ib = w>>2, phase qq = w&3 (rows stride 8)
  const int ib = wave >> 2, qq = wave & 3;
  const int bb = b0 + ib;
  const int start = offs[bb], end = offs[bb + 1];

  v4f q4 = *(const v4f*)(bqt + lane * 4);
  #pragma unroll
  for (int w = 0; w < 4; ++w) q4 += *(const v4f*)&partq[w][ib][lane * 4];
  __syncthreads();   // partq dead; ss region may now be written

  float m = -1e30f, den = 0.f;
  v4f acc = {0.f, 0.f, 0.f, 0.f};
  {
    const float SC = 0.0625f * LOG2E;
    const int odd = lane & 1;
    int n = start + qq * 2;
    v4f c0 = ldg_nt(H + (size_t)n * D + lane * 4, n < end);
    v4f c1 = ldg_nt(H + (size_t)(n + 1) * D + lane * 4, n + 1 < end);
    v4f e0 = ldg_nt(H + (size_t)(n + 8) * D + lane * 4, n + 8 < end);
    v4f e1 = ldg_nt(H + (size_t)(n + 9) * D + lane * 4, n + 9 < end);
    while (n < end) {
      const int nf = n + 16;
      v4f g0 = ldg_nt(H + (size_t)nf * D + lane * 4, nf < end);
      v4f g1 = ldg_nt(H + (size_t)(nf + 1) * D + lane * 4, nf + 1 < end);

      const float d0 = dot4(c0, q4);
      const float d1 = dot4(c1, q4);
      const float mine = odd ? d1 : d0;
      const float oth  = odd ? d0 : d1;
      float s = mine + __shfl_xor(oth, 1);
      s += __shfl_xor(s, 2);
      s += __shfl_xor(s, 4);
      s += __shfl_xor(s, 8);
      s += __shfl_xor(s, 16);
      s += __shfl_xor(s, 32);
      const float sc = (n + odd < end) ? s * SC : -1e30f;

      const float mm = fmaxf(sc, __shfl_xor(sc, 1));
      const float nm = fmaxf(m, mm);
      const float f = exp2f(m - nm);
      const float w = exp2f(sc - nm);
      const float wx = __shfl_xor(w, 1);
      const float wr0 = odd ? wx : w;
      const float wr1 = odd ? w : wx;
      den = fmaf(den, f, w + wx);
      acc = acc * f + c0 * wr0 + c1 * wr1;
      m = nm;

      c0 = e0; c1 = e1; e0 = g0; e1 = g1; n += 8;
    }
  }
  *(v4f*)&ss[wave][lane * 4] = acc;
  if (lane == 0) { sm[wave] = m; sd[wave] = den; }
  __syncthreads();

  // ---- merge 4 phase-waves per batch -> Us2 = [V ; s_norm]
  {
    const int i = t >> 8, d = t & 255;
    const int w0 = i * 4;
    const float m0 = sm[w0], m1 = sm[w0 + 1], m2 = sm[w0 + 2], m3 = sm[w0 + 3];
    const float M = fmaxf(fmaxf(m0, m1), fmaxf(m2, m3));
    const float f0 = exp2f(m0 - M), f1 = exp2f(m1 - M);
    const float f2 = exp2f(m2 - M), f3 = exp2f(m3 - M);
    const float Dn = sd[w0] * f0 + sd[w0 + 1] * f1 + sd[w0 + 2] * f2 + sd[w0 + 3] * f3;
    const float inv = (Dn > 0.f) ? (1.f / Dn) : 0.f;
    const float sv = (ss[w0][d] * f0 + ss[w0 + 1][d] * f1 +
                      ss[w0 + 2][d] * f2 + ss[w0 + 3][d] * f3) * inv;
    Us2[d * 2 + i] = Vs[i * 256 + d];
    Us2[(D + d) * 2 + i] = sv;
  }
  __syncthreads();

  // ---- epilogue: out = WfT^T Us2 + c ; wave covers k in [wave*64,+64) of K=512
  {
    v4f a0 = {0.f, 0.f, 0.f, 0.f}, a1 = a0;
    const int kb = wave * 64;
    #pragma unroll 4
    for (int kk = 0; kk < 64; ++kk) {
      const int k = kb + kk;
      const v4f w4 = *(const v4f*)(WfT + (size_t)k * D + lane * 4);
      const float2 u2 = *(const float2*)&Us2[k * 2];   // b64 broadcast
      a0 += w4 * u2.x;
      a1 += w4 * u2.y;
    }
    if (wave >= 4) {
      *(v4f*)&part[wave - 4][0][lane * 4] = a0;
      *(v4f*)&part[wave - 4][1][lane * 4] = a1;
    }
    __syncthreads();
    if (wave < 4) {
      v4f p0 = *(const v4f*)&part[wave][0][lane * 4];
      v4f p1 = *(const v4f*)&part[wave][1][lane * 4];
      *(v4f*)&part[wave][0][lane * 4] = a0 + p0;
      *(v4f*)&part[wave][1][lane * 4] = a1 + p1;
    }
  }
  __syncthreads();
  {
    const int i = t >> 8, d = t & 255;
    const int bb2 = b0 + i;
    float s = cvec[d];
    #pragma unroll
    for (int w = 0; w < 4; ++w) s += part[w][i][d];
    const int c = offs[bb2 + 1] - offs[bb2];
    out[(size_t)bb2 * D + d] = (c > 0) ? s : Vs[i * 256 + d];
  }
}

extern "C" void kernel_launch(void* const* d_in, const int* in_sizes, int n_in,
                              void* d_out, int out_size, void* d_ws, size_t ws_size,
                              hipStream_t stream) {
  const float* V   = (const float*)d_in[0];
  const float* H   = (const float*)d_in[1];
  const int* bidx  = (const int*)d_in[2];
  const float* Wq  = (const float*)d_in[3];
  const float* bq  = (const float*)d_in[4];
  const float* Wk  = (const float*)d_in[5];
  const float* Wv  = (const float*)d_in[7];
  const float* bv  = (const float*)d_in[8];
  const float* Wo  = (const float*)d_in[9];
  const float* bo  = (const float*)d_in[10];
  float* out = (float*)d_out;

  float* ws  = (float*)d_ws;
  float* Mt  = ws;                       // 256*256
  float* WfT = Mt + D * D;               // 512*256
  float* bqt = WfT + TWOD * D;           // 256
  float* cv  = bqt + D;                  // 256
  int* offs  = (int*)(cv + D);           // 1025

  hipLaunchKernelGGL(prep_kernel, dim3(658), dim3(256), 0, stream,
                     Wq, bq, Wk, Wv, bv, Wo, bo, bidx,
                     Mt, WfT, bqt, cv, offs);
  hipLaunchKernelGGL(f_kernel, dim3(BB / 2), dim3(512), 0, stream,
                     H, V, Mt, bqt, offs, WfT, cv, out);
}

// Round 10
// 46.664 us; speedup vs baseline: 1.0843x; 1.0843x over previous
//
#include <hip/hip_runtime.h>
#include <math.h>

#define D 256
#define TWOD 512
#define BB 1024
#define NN 131072
#define LOG2E 1.4426950408889634f

typedef float v4f __attribute__((ext_vector_type(4)));

__device__ __forceinline__ v4f ldg_nt(const float* p, bool valid) {
  v4f z = {0.f, 0.f, 0.f, 0.f};
  if (valid) z = __builtin_nontemporal_load((const v4f*)p);
  return z;
}

__device__ __forceinline__ float dot4(v4f a, v4f b) {
  return fmaf(a.w, b.w, fmaf(a.z, b.z, fmaf(a.y, b.y, a.x * b.x)));
}

// ---------------- prep:
// blocks 0..63    : Mt[d][k] = sum_e Wq[e][d]*Wk[e][k]   (4 d-rows/block, e split over waves)
// blocks 64..127  : WfT[256+h][d] = (Wo_B @ Wv)[d][h]    (4 h/block)
// blocks 128..143 : WfT[k][d] = Wo[d][k]                 (transpose of Wo_A)
// block 144       : bqt[k] = sum_e Wk[e][k]*bq[e]
// block 145       : c[d] = bo[d] + sum_v Wo[d][256+v]*bv[v]
// blocks 146..657 : offs scatter
__global__ __launch_bounds__(256) void prep_kernel(
    const float* __restrict__ Wq, const float* __restrict__ bq,
    const float* __restrict__ Wk, const float* __restrict__ Wv,
    const float* __restrict__ bv, const float* __restrict__ Wo,
    const float* __restrict__ bo, const int* __restrict__ bidx,
    float* __restrict__ Mt, float* __restrict__ WfT,
    float* __restrict__ bqt, float* __restrict__ cvec,
    int* __restrict__ offs) {
  const int blk = blockIdx.x;
  const int t = threadIdx.x;
  if (blk < 64) {
    __shared__ __align__(16) float part[4][4][D];   // 16 KB
    const int wq = t >> 6, lane = t & 63;
    const int d0 = blk * 4;
    v4f a0 = {0.f, 0.f, 0.f, 0.f}, a1 = a0, a2 = a0, a3 = a0;
    for (int ee = 0; ee < 64; ++ee) {
      const int e = wq * 64 + ee;
      const v4f wk4 = *(const v4f*)&Wk[(size_t)e * D + lane * 4];  // coalesced
      const float* wqr = Wq + (size_t)e * D + d0;                  // uniform -> sgpr
      a0 += wk4 * wqr[0];
      a1 += wk4 * wqr[1];
      a2 += wk4 * wqr[2];
      a3 += wk4 * wqr[3];
    }
    *(v4f*)&part[wq][0][lane * 4] = a0;
    *(v4f*)&part[wq][1][lane * 4] = a1;
    *(v4f*)&part[wq][2][lane * 4] = a2;
    *(v4f*)&part[wq][3][lane * 4] = a3;
    __syncthreads();
    #pragma unroll
    for (int r = 0; r < 4; ++r)
      Mt[(size_t)(d0 + r) * D + t] =
          part[0][r][t] + part[1][r][t] + part[2][r][t] + part[3][r][t];
  } else if (blk < 128) {
    const int h0 = (blk - 64) * 4;
    float a0 = 0.f, a1 = 0.f, a2 = 0.f, a3 = 0.f;
    for (int v = 0; v < D; ++v) {
      const float wo = Wo[(size_t)t * TWOD + D + v]; // per-lane own-row walk (L1)
      const float* wvr = Wv + (size_t)v * D + h0;    // uniform -> sgpr
      a0 = fmaf(wvr[0], wo, a0);
      a1 = fmaf(wvr[1], wo, a1);
      a2 = fmaf(wvr[2], wo, a2);
      a3 = fmaf(wvr[3], wo, a3);
    }
    WfT[(size_t)(D + h0 + 0) * D + t] = a0;
    WfT[(size_t)(D + h0 + 1) * D + t] = a1;
    WfT[(size_t)(D + h0 + 2) * D + t] = a2;
    WfT[(size_t)(D + h0 + 3) * D + t] = a3;
  } else if (blk < 144) {
    __shared__ float tile[64][65];
    const int b = blk - 128;
    const int r0 = (b >> 2) * 64, c0 = (b & 3) * 64;
    const int lane = t & 63, sr = t >> 6;
    #pragma unroll 4
    for (int rr = 0; rr < 16; ++rr) {
      const int r = rr * 4 + sr;
      tile[r][lane] = Wo[(size_t)(r0 + r) * TWOD + c0 + lane];
    }
    __syncthreads();
    #pragma unroll 4
    for (int rr = 0; rr < 16; ++rr) {
      const int r = rr * 4 + sr;
      WfT[(size_t)(c0 + r) * D + r0 + lane] = tile[lane][r];
    }
  } else if (blk == 144) {
    float a = 0.f;
    for (int e = 0; e < D; ++e)
      a = fmaf(Wk[(size_t)e * D + t], bq[e], a);
    bqt[t] = a;
  } else if (blk == 145) {
    float a = bo[t];
    for (int v = 0; v < D; ++v)
      a = fmaf(Wo[(size_t)t * TWOD + D + v], bv[v], a);
    cvec[t] = a;
  } else {
    const int i = (blk - 146) * 256 + t;
    if (i >= NN) return;
    const int b1 = bidx[i];
    const int b2 = (i + 1 < NN) ? bidx[i + 1] : BB;
    if (i == 0) {
      for (int b = 0; b <= b1; ++b) offs[b] = 0;
    }
    for (int b = b1 + 1; b <= b2; ++b) offs[b] = i + 1;
  }
}

// ---------------- fused: qt-GEMV + balanced flash + merge + epilogue GEMV, 4 batches/block
__global__ __launch_bounds__(1024) void f_kernel(
    const float* __restrict__ H, const float* __restrict__ V,
    const float* __restrict__ Mt, const float* __restrict__ bqt,
    const int* __restrict__ offs, const float* __restrict__ WfT,
    const float* __restrict__ cvec, float* __restrict__ out) {
  __shared__ __align__(16) char smem[32768 + 4096 + 8192];
  // region A [0,32768): partq[8][4][256] -> flash ss[16][256] -> epi part[8][4][256]
  // region B [32768,36864): Vs[4][256]
  // region C [36864,45056): Us2[512][4]
  float (*partq)[4][D] = (float(*)[4][D])smem;
  float (*ss)[D] = (float(*)[D])smem;
  float (*part)[4][D] = (float(*)[4][D])smem;
  float* Vs  = (float*)(smem + 32768);
  float* Us2 = (float*)(smem + 36864);
  __shared__ float sm[16], sd[16];
  __shared__ int soff[5];     // offs[b0..b0+4]
  __shared__ int wpre[5];     // wave prefix per batch

  const int t = threadIdx.x;
  const int wave = t >> 6, lane = t & 63;
  const int blk = blockIdx.x;
  const int b0 = blk * 4;

  // ---- stage V + apportion 16 waves over 4 batches (Hamilton, thread 0)
  {
    const int i = t >> 8, d = t & 255;
    Vs[i * 256 + d] = V[(size_t)(b0 + i) * D + d];
  }
  if (t == 0) {
    int c[4], C = 0, ne = 0;
    #pragma unroll
    for (int i = 0; i < 4; ++i) {
      soff[i] = offs[b0 + i];
    }
    soff[4] = offs[b0 + 4];
    #pragma unroll
    for (int i = 0; i < 4; ++i) {
      c[i] = soff[i + 1] - soff[i];
      C += c[i];
      if (c[i] > 0) ne++;
    }
    int w[4] = {0, 0, 0, 0};
    if (C > 0) {
      const int R = 16 - ne;
      long rem[4];
      int sumex = 0;
      #pragma unroll
      for (int i = 0; i < 4; ++i) {
        if (c[i] > 0) {
          const long num = (long)R * c[i];
          const int ex = (int)(num / C);
          w[i] = 1 + ex;
          rem[i] = num - (long)ex * C;
          sumex += ex;
        } else {
          rem[i] = -1;
        }
      }
      int L = R - sumex;
      while (L > 0) {
        int arg = 0;
        long best = -2;
        #pragma unroll
        for (int i = 0; i < 4; ++i)
          if (rem[i] > best) { best = rem[i]; arg = i; }
        w[arg] += 1;
        rem[arg] = -2;
        --L;
      }
    }
    wpre[0] = 0;
    #pragma unroll
    for (int i = 0; i < 4; ++i) wpre[i + 1] = wpre[i] + w[i];
  }
  __syncthreads();

  // ---- wave -> (batch, phase, width); issue first flash loads EARLY
  int myi = -1, ph = 0, nw = 1;
  #pragma unroll
  for (int i = 0; i < 4; ++i)
    if (wave >= wpre[i] && wave < wpre[i + 1]) { myi = i; ph = wave - wpre[i]; nw = wpre[i + 1] - wpre[i]; }
  const int start = (myi >= 0) ? soff[myi] : 0;
  const int end   = (myi >= 0) ? soff[myi + 1] : 0;
  const int S2 = 2 * nw;
  int n = start + ph * 2;
  v4f c0 = ldg_nt(H + (size_t)n * D + lane * 4, n < end);
  v4f c1 = ldg_nt(H + (size_t)(n + 1) * D + lane * 4, n + 1 < end);

  // ---- qt prologue: qt = Mt^T V + bqt ; wave covers d in [wave*16,+16)
  {
    v4f a0 = {0.f, 0.f, 0.f, 0.f}, a1 = a0, a2 = a0, a3 = a0;
    const int db = wave * 16;
    #pragma unroll 4
    for (int dd = 0; dd < 16; ++dd) {
      const int d = db + dd;
      const v4f w4 = *(const v4f*)(Mt + (size_t)d * D + lane * 4);
      a0 += w4 * Vs[0 * 256 + d];
      a1 += w4 * Vs[1 * 256 + d];
      a2 += w4 * Vs[2 * 256 + d];
      a3 += w4 * Vs[3 * 256 + d];
    }
    if (wave >= 8) {
      *(v4f*)&partq[wave - 8][0][lane * 4] = a0;
      *(v4f*)&partq[wave - 8][1][lane * 4] = a1;
      *(v4f*)&partq[wave - 8][2][lane * 4] = a2;
      *(v4f*)&partq[wave - 8][3][lane * 4] = a3;
    }
    __syncthreads();
    if (wave < 8) {
      v4f p0 = *(const v4f*)&partq[wave][0][lane * 4];
      v4f p1 = *(const v4f*)&partq[wave][1][lane * 4];
      v4f p2 = *(const v4f*)&partq[wave][2][lane * 4];
      v4f p3 = *(const v4f*)&partq[wave][3][lane * 4];
      *(v4f*)&partq[wave][0][lane * 4] = a0 + p0;
      *(v4f*)&partq[wave][1][lane * 4] = a1 + p1;
      *(v4f*)&partq[wave][2][lane * 4] = a2 + p2;
      *(v4f*)&partq[wave][3][lane * 4] = a3 + p3;
    }
  }
  __syncthreads();

  // ---- assemble q4 for this wave's batch
  const int qb = (myi >= 0) ? myi : 0;
  v4f q4 = *(const v4f*)(bqt + lane * 4);
  #pragma unroll
  for (int w = 0; w < 8; ++w) q4 += *(const v4f*)&partq[w][qb][lane * 4];
  __syncthreads();   // partq dead; ss region may now be written

  // ---- flash: rows n, n+1, stride S2
  float m = -1e30f, den = 0.f;
  v4f acc = {0.f, 0.f, 0.f, 0.f};
  {
    const float SC = 0.0625f * LOG2E;
    const int odd = lane & 1;
    while (n < end) {
      const int nn = n + S2;
      v4f p0 = ldg_nt(H + (size_t)nn * D + lane * 4, nn < end);
      v4f p1 = ldg_nt(H + (size_t)(nn + 1) * D + lane * 4, nn + 1 < end);

      const float d0 = dot4(c0, q4);
      const float d1 = dot4(c1, q4);
      const float mine = odd ? d1 : d0;
      const float oth  = odd ? d0 : d1;
      float s = mine + __shfl_xor(oth, 1);
      s += __shfl_xor(s, 2);
      s += __shfl_xor(s, 4);
      s += __shfl_xor(s, 8);
      s += __shfl_xor(s, 16);
      s += __shfl_xor(s, 32);
      const float sc = (n + odd < end) ? s * SC : -1e30f;

      const float mm = fmaxf(sc, __shfl_xor(sc, 1));
      const float nm = fmaxf(m, mm);
      const float f = exp2f(m - nm);
      const float w = exp2f(sc - nm);
      const float wx = __shfl_xor(w, 1);
      const float wr0 = odd ? wx : w;
      const float wr1 = odd ? w : wx;
      den = fmaf(den, f, w + wx);
      acc = acc * f + c0 * wr0 + c1 * wr1;
      m = nm;

      c0 = p0; c1 = p1; n = nn;
    }
  }
  *(v4f*)&ss[wave][lane * 4] = acc;
  if (lane == 0) { sm[wave] = m; sd[wave] = den; }
  __syncthreads();

  // ---- merge variable wave ranges per batch -> Us2 = [V ; s_norm]
  {
    const int i = t >> 8, d = t & 255;
    const int W0 = wpre[i], W1 = wpre[i + 1];
    float M = -1e30f;
    for (int w = W0; w < W1; ++w) M = fmaxf(M, sm[w]);
    float Dn = 0.f, sv = 0.f;
    for (int w = W0; w < W1; ++w) {
      const float f = exp2f(sm[w] - M);
      Dn = fmaf(sd[w], f, Dn);
      sv = fmaf(ss[w][d], f, sv);
    }
    const float inv = (Dn > 0.f) ? (1.f / Dn) : 0.f;
    Us2[d * 4 + i] = Vs[i * 256 + d];
    Us2[(D + d) * 4 + i] = sv * inv;
  }
  __syncthreads();

  // ---- epilogue: out = WfT^T Us2 + c ; wave covers k in [wave*32,+32) of K=512
  {
    v4f a0 = {0.f, 0.f, 0.f, 0.f}, a1 = a0, a2 = a0, a3 = a0;
    const int kb = wave * 32;
    #pragma unroll 4
    for (int kk = 0; kk < 32; ++kk) {
      const int k = kb + kk;
      const v4f w4 = *(const v4f*)(WfT + (size_t)k * D + lane * 4);
      const v4f u4 = *(const v4f*)&Us2[k * 4];     // b128 broadcast
      a0 += w4 * u4.x; a1 += w4 * u4.y; a2 += w4 * u4.z; a3 += w4 * u4.w;
    }
    if (wave >= 8) {
      *(v4f*)&part[wave - 8][0][lane * 4] = a0;
      *(v4f*)&part[wave - 8][1][lane * 4] = a1;
      *(v4f*)&part[wave - 8][2][lane * 4] = a2;
      *(v4f*)&part[wave - 8][3][lane * 4] = a3;
    }
    __syncthreads();
    if (wave < 8) {
      v4f p0 = *(const v4f*)&part[wave][0][lane * 4];
      v4f p1 = *(const v4f*)&part[wave][1][lane * 4];
      v4f p2 = *(const v4f*)&part[wave][2][lane * 4];
      v4f p3 = *(const v4f*)&part[wave][3][lane * 4];
      *(v4f*)&part[wave][0][lane * 4] = a0 + p0;
      *(v4f*)&part[wave][1][lane * 4] = a1 + p1;
      *(v4f*)&part[wave][2][lane * 4] = a2 + p2;
      *(v4f*)&part[wave][3][lane * 4] = a3 + p3;
    }
  }
  __syncthreads();
  {
    const int i = t >> 8, d = t & 255;
    const int bb2 = b0 + i;
    float s = cvec[d];
    #pragma unroll
    for (int w = 0; w < 8; ++w) s += part[w][i][d];
    const int c = soff[i + 1] - soff[i];
    out[(size_t)bb2 * D + d] = (c > 0) ? s : Us2[d * 4 + i];
  }
}

extern "C" void kernel_launch(void* const* d_in, const int* in_sizes, int n_in,
                              void* d_out, int out_size, void* d_ws, size_t ws_size,
                              hipStream_t stream) {
  const float* V   = (const float*)d_in[0];
  const float* H   = (const float*)d_in[1];
  const int* bidx  = (const int*)d_in[2];
  const float* Wq  = (const float*)d_in[3];
  const float* bq  = (const float*)d_in[4];
  const float* Wk  = (const float*)d_in[5];
  const float* Wv  = (const float*)d_in[7];
  const float* bv  = (const float*)d_in[8];
  const float* Wo  = (const float*)d_in[9];
  const float* bo  = (const float*)d_in[10];
  float* out = (float*)d_out;

  float* ws  = (float*)d_ws;
  float* Mt  = ws;                       // 256*256
  float* WfT = Mt + D * D;               // 512*256
  float* bqt = WfT + TWOD * D;           // 256
  float* cv  = bqt + D;                  // 256
  int* offs  = (int*)(cv + D);           // 1025

  hipLaunchKernelGGL(prep_kernel, dim3(658), dim3(256), 0, stream,
                     Wq, bq, Wk, Wv, bv, Wo, bo, bidx,
                     Mt, WfT, bqt, cv, offs);
  hipLaunchKernelGGL(f_kernel, dim3(BB / 4), dim3(1024), 0, stream,
                     H, V, Mt, bqt, offs, WfT, cv, out);
}